// Round 2
// baseline (90.856 us; speedup 1.0000x reference)
//
#include <hip/hip_runtime.h>
#include <hip/hip_bf16.h>

// Problem: B=16, L=4096, H=256, fp32 in/out.
// out = x + T @ (x @ Wv^T @ Wo^T), T = causal uniform average.
// Reformulated: W = Wo@Wv (bf16); S = cumsum_L(x);
//               out = x + (S @ W^T) * (1/(i+1)).
// Round 2: cumsum fused INTO the GEMM (chunk-local scan per block, offsets
// from K2/K3). No Sbf round-trip. As is ds_write-staged -> XOR-swizzled
// (kills the 16-way bank conflict). W read straight from L2 (no B-tile LDS)
// -> barrier-free K-loop, 64KB LDS, 2 blocks/CU.

#define B_  16
#define L_  4096
#define H_  256
#define M_  (B_*L_)      // 65536 rows
#define CH  64           // 64-row chunks per sequence (for offset kernels)
#define CHROWS 64

typedef short short8 __attribute__((ext_vector_type(8)));
typedef float f32x4  __attribute__((ext_vector_type(4)));

__device__ __forceinline__ unsigned short f2bf(float f) {
  unsigned int u = __builtin_bit_cast(unsigned int, f);
  u += 0x7fffu + ((u >> 16) & 1u);          // round-to-nearest-even
  return (unsigned short)(u >> 16);
}

// ---------------- K1: W = Wo @ Wv -> bf16 row-major [H][H] ----------------
__global__ void fuse_w_kernel(const float* __restrict__ Wv,
                              const float* __restrict__ Wo,
                              unsigned short* __restrict__ Wbf) {
  __shared__ float wo[H_];
  int h = blockIdx.x, t = threadIdx.x;
  wo[t] = Wo[h*H_ + t];
  __syncthreads();
  float acc = 0.f;
  #pragma unroll 8
  for (int m = 0; m < H_; ++m) acc += wo[m] * Wv[m*H_ + t];
  Wbf[h*H_ + t] = f2bf(acc);
}

// ---------------- K2: per-chunk column sums of x ----------------
__global__ void partial_kernel(const float* __restrict__ x, float* __restrict__ P) {
  int c = blockIdx.x, b = blockIdx.y, t = threadIdx.x;
  const float* p = x + ((size_t)(b*L_ + c*CHROWS))*H_ + t;
  float s = 0.f;
  #pragma unroll 8
  for (int r = 0; r < CHROWS; ++r) s += p[(size_t)r*H_];
  P[(b*CH + c)*H_ + t] = s;
}

// ---------------- K3: exclusive scan of chunk sums (tiny) ----------------
__global__ void scan_kernel(const float* __restrict__ P, float* __restrict__ O) {
  int b = blockIdx.x, t = threadIdx.x;
  float run = 0.f;
  #pragma unroll
  for (int c = 0; c < CH; ++c) {
    int idx = (b*CH + c)*H_ + t;
    O[idx] = run;
    run += P[idx];
  }
}

// ------- K4: fused {chunk cumsum -> bf16 LDS} + {S @ W^T} + epilogue -------
// BM=128 rows/block, BN=256 (full width). 512 threads = 8 waves (2x4).
// As: [128 rows][256 k] bf16, XOR-swizzled: phys_colbyte = colbyte ^ ((row&7)<<4).
#define BM 128

__global__ __launch_bounds__(512, 2) void gemm_fused(
    const float* __restrict__ x,
    const unsigned short* __restrict__ Wbf,   // [H][H] bf16 row-major
    const float* __restrict__ O,              // [B][CH][H] exclusive chunk prefixes
    float* __restrict__ out) {
  __shared__ __align__(16) unsigned short As[BM * H_];   // 64KB
  char* Asb = (char*)As;

  const int tid = threadIdx.x;
  const int rowBase = blockIdx.x * BM;          // global row
  const int b  = rowBase >> 12;                 // sequence index
  const int ri = rowBase & (L_ - 1);            // row within sequence

  // ---- phase 1: chunk-local inclusive cumsum of x -> swizzled bf16 As ----
  if (tid < H_) {
    const int t = tid;                          // column
    float run = O[((b << 6) + (ri >> 6)) * H_ + t];
    const float* xp = x + (size_t)rowBase * H_ + t;
    #pragma unroll 8
    for (int r = 0; r < BM; ++r) {
      run += xp[(size_t)r * H_];
      int pc = (2*t) ^ ((r & 7) << 4);          // swizzled col-byte
      *(unsigned short*)(Asb + r*512 + pc) = f2bf(run);
    }
  }
  __syncthreads();

  // ---- phase 2: GEMM. 8 waves as 2(rows) x 4(cols); wave tile 64x64 ----
  const int wave = tid >> 6, lane = tid & 63;
  const int wr = wave >> 2, wc = wave & 3;
  const int lrow = lane & 15;                   // fragment row/col index
  const int lk   = lane >> 4;                   // k-group (8 elems)

  f32x4 acc[4][4] = {};

  for (int k0 = 0; k0 < H_; k0 += 64) {
    #pragma unroll
    for (int ks = 0; ks < 2; ++ks) {
      // B fragments straight from global (W is L2-resident, 128KB total)
      short8 bf[4];
      #pragma unroll
      for (int n = 0; n < 4; ++n) {
        int wrow = wc*64 + n*16 + lrow;         // W row == output col
        bf[n] = *(const short8*)(Wbf + (size_t)wrow*H_ + k0 + ks*32 + lk*8);
      }
      // A fragments from swizzled LDS
      short8 af[4];
      #pragma unroll
      for (int i = 0; i < 4; ++i) {
        int ar = wr*64 + i*16 + lrow;
        int cb = (k0*2 + ks*64 + lk*16) ^ ((ar & 7) << 4);
        af[i] = *(const short8*)(Asb + ar*512 + cb);
      }
      #pragma unroll
      for (int i = 0; i < 4; ++i)
        #pragma unroll
        for (int n = 0; n < 4; ++n)
          acc[i][n] = __builtin_amdgcn_mfma_f32_16x16x32_bf16(af[i], bf[n], acc[i][n], 0, 0, 0);
    }
  }

  // ---- phase 3: out = x + acc / (i+1) ----
  #pragma unroll
  for (int i = 0; i < 4; ++i) {
    #pragma unroll
    for (int j4 = 0; j4 < 4; ++j4) {
      int row = rowBase + wr*64 + i*16 + lk*4 + j4;
      float scale = 1.0f / (float)((row & (L_ - 1)) + 1);
      size_t rb = (size_t)row * H_;
      #pragma unroll
      for (int n = 0; n < 4; ++n) {
        int col = wc*64 + n*16 + lrow;
        out[rb + col] = x[rb + col] + acc[i][n][j4] * scale;
      }
    }
  }
}

extern "C" void kernel_launch(void* const* d_in, const int* in_sizes, int n_in,
                              void* d_out, int out_size, void* d_ws, size_t ws_size,
                              hipStream_t stream) {
  const float* x  = (const float*)d_in[0];
  const float* Wv = (const float*)d_in[1];
  const float* Wo = (const float*)d_in[2];
  float* out = (float*)d_out;

  char* ws = (char*)d_ws;
  unsigned short* Wbf = (unsigned short*)ws;                    // 128KB
  float* P = (float*)(ws + (size_t)H_*H_*2);                    // 1MB
  float* Off = P + B_*CH*H_;                                    // 1MB

  hipLaunchKernelGGL(fuse_w_kernel,  dim3(H_),     dim3(H_), 0, stream, Wv, Wo, Wbf);
  hipLaunchKernelGGL(partial_kernel, dim3(CH, B_), dim3(H_), 0, stream, x, P);
  hipLaunchKernelGGL(scan_kernel,    dim3(B_),     dim3(H_), 0, stream, P, Off);
  hipLaunchKernelGGL(gemm_fused,     dim3(M_/BM),  dim3(512), 0, stream,
                     x, Wbf, Off, out);
}

// Round 3
// 84.918 us; speedup vs baseline: 1.0699x; 1.0699x over previous
//
#include <hip/hip_runtime.h>
#include <hip/hip_bf16.h>

// out = x + T @ (x @ Wv^T @ Wo^T), T = causal uniform average. fp32, B=16,L=4096,H=256.
// W = Wo@Wv (bf16). Per 128-row block: Y = Xbf @ W^T (MFMA), then in-register
// wave-parallel causal prefix over Y rows (+ LDS colsum for cross-half,
// + carry Z = O'@W^T computed in-kernel), epilogue out = x + (P+base)/(i+1).

#define B_  16
#define L_  4096
#define H_  256
#define M_  (B_*L_)
#define CH  64
#define CHROWS 64
#define BM 128

typedef short short4v __attribute__((ext_vector_type(4)));
typedef short short8  __attribute__((ext_vector_type(8)));
typedef float f32x4   __attribute__((ext_vector_type(4)));

__device__ __forceinline__ unsigned short f2bf(float f) {
  unsigned int u = __builtin_bit_cast(unsigned int, f);
  u += 0x7fffu + ((u >> 16) & 1u);
  return (unsigned short)(u >> 16);
}
__device__ __forceinline__ float bf2f(unsigned short s) {
  unsigned int u = ((unsigned int)s) << 16;
  return __builtin_bit_cast(float, u);
}

// ---------------- K1: W = Wo @ Wv -> bf16 row-major [H][H] ----------------
__global__ void fuse_w_kernel(const float* __restrict__ Wv,
                              const float* __restrict__ Wo,
                              unsigned short* __restrict__ Wbf) {
  __shared__ float wo[H_];
  int h = blockIdx.x, t = threadIdx.x;
  wo[t] = Wo[h*H_ + t];
  __syncthreads();
  float acc = 0.f;
  #pragma unroll 8
  for (int m = 0; m < H_; ++m) acc += wo[m] * Wv[m*H_ + t];
  Wbf[h*H_ + t] = f2bf(acc);
}

// ---------------- K2: per-64-row-chunk column sums of x ----------------
__global__ void partial_kernel(const float* __restrict__ x, float* __restrict__ P) {
  int c = blockIdx.x, b = blockIdx.y, t = threadIdx.x;
  const float* p = x + ((size_t)(b*L_ + c*CHROWS))*H_ + t;
  float s = 0.f;
  #pragma unroll 8
  for (int r = 0; r < CHROWS; ++r) s += p[(size_t)r*H_];
  P[(b*CH + c)*H_ + t] = s;
}

// ---------------- K3: exclusive scan of chunk sums (tiny) ----------------
__global__ void scan_kernel(const float* __restrict__ P, float* __restrict__ O) {
  int b = blockIdx.x, t = threadIdx.x;
  float run = 0.f;
  #pragma unroll
  for (int c = 0; c < CH; ++c) {
    int idx = (b*CH + c)*H_ + t;
    O[idx] = run;
    run += P[idx];
  }
}

// ---------------- K4: main fused kernel ----------------
// 512 threads = 8 waves (wr=wave>>2 in {0,1}: 64-row half; wc=wave&3: 64-col group).
// LDS (dynamic 67584B): [0,64K) Xs bf16 [128][256] XOR-swizzled; zbuf[256]; csum[256].
__global__ __launch_bounds__(512, 4) void main_kernel(
    const float* __restrict__ x,
    const unsigned short* __restrict__ Wbf,
    const float* __restrict__ Op,          // [B*CH][H] exclusive 64-row prefixes
    float* __restrict__ out) {
  extern __shared__ char smem[];
  float* zbuf = (float*)(smem + 65536);
  float* csum = zbuf + 256;

  const int tid = threadIdx.x;
  const int lane = tid & 63, wave = tid >> 6;
  const int rowBase = blockIdx.x * BM;

  // ---- phase A: stage X tile -> bf16 swizzled LDS (coalesced float4) ----
  #pragma unroll 4
  for (int it = 0; it < 16; ++it) {
    int r = it*8 + wave;
    const float4 v = *(const float4*)(x + (size_t)(rowBase + r)*H_ + lane*4);
    short4v s;
    s[0] = (short)f2bf(v.x); s[1] = (short)f2bf(v.y);
    s[2] = (short)f2bf(v.z); s[3] = (short)f2bf(v.w);
    *(short4v*)(smem + r*512 + ((lane*8) ^ ((r & 7) << 4))) = s;
  }
  __syncthreads();

  // ---- Z-dot (waves 0-3, overlaps waves 4-7's GEMM1): z[c] = O'row . W[c] ----
  if (tid < H_) {
    const float* op = Op + (size_t)blockIdx.x * 2 * H_;   // 128-row-grain prefix
    float z = 0.f;
    #pragma unroll 4
    for (int kk = 0; kk < 32; ++kk) {
      short8 w8 = *(const short8*)(Wbf + (size_t)tid*H_ + kk*8);
      #pragma unroll
      for (int e = 0; e < 8; ++e)
        z += op[kk*8 + e] * bf2f((unsigned short)w8[e]);
    }
    zbuf[tid] = z;
  }

  // ---- GEMM1: acc = Xbf @ W^T (wave tile 64x64, K=256) ----
  const int wr = wave >> 2, wc = wave & 3;
  const int lrow = lane & 15, g = lane >> 4;

  f32x4 acc[4][4] = {};
  #pragma unroll
  for (int k0 = 0; k0 < H_; k0 += 64) {
    #pragma unroll
    for (int ks = 0; ks < 2; ++ks) {
      short8 bfr[4], af[4];
      #pragma unroll
      for (int n = 0; n < 4; ++n) {
        int wrow = wc*64 + n*16 + lrow;
        bfr[n] = *(const short8*)(Wbf + (size_t)wrow*H_ + k0 + ks*32 + g*8);
      }
      #pragma unroll
      for (int i = 0; i < 4; ++i) {
        int ar = wr*64 + i*16 + lrow;
        int cb = (k0*2 + ks*64 + g*16) ^ ((ar & 7) << 4);
        af[i] = *(const short8*)(smem + ar*512 + cb);
      }
      #pragma unroll
      for (int i = 0; i < 4; ++i)
        #pragma unroll
        for (int n = 0; n < 4; ++n)
          acc[i][n] = __builtin_amdgcn_mfma_f32_16x16x32_bf16(af[i], bfr[n], acc[i][n], 0, 0, 0);
    }
  }

  // ---- in-register causal prefix over this wave's 64 rows ----
  // C-layout: value (i,n,q) = Y[row = wr*64 + i*16 + g*4 + q][col = wc*64 + n*16 + lrow]
  #pragma unroll
  for (int n = 0; n < 4; ++n) {
    float run = 0.f;
    #pragma unroll
    for (int i = 0; i < 4; ++i) {
      f32x4 a = acc[i][n];
      a[1] += a[0]; a[2] += a[1]; a[3] += a[2];   // q-inclusive prefix
      float Bv = a[3];                             // 4-row block total
      float v = Bv;
      float t = __shfl_up(v, 16);
      if (lane >= 16) v += t;
      t = __shfl_up(v, 32);
      if (lane >= 32) v += t;                      // g-inclusive
      float gex = v - Bv;                          // g-exclusive
      float tot = __shfl(v, lrow + 48);            // 16-row total
      float addv = gex + run;
      a[0] += addv; a[1] += addv; a[2] += addv; a[3] += addv;
      acc[i][n] = a;
      run += tot;
    }
    // run == this wave's 64-row column total (uniform over g)
    if (wr == 0 && g == 0) csum[wc*64 + n*16 + lrow] = run;
  }
  __syncthreads();

  // ---- epilogue: out = x + (P + zbuf + (wr?csum:0)) / (row+1) ----
  float base[4];
  #pragma unroll
  for (int n = 0; n < 4; ++n) {
    int c = wc*64 + n*16 + lrow;
    base[n] = zbuf[c] + (wr ? csum[c] : 0.f);
  }
  #pragma unroll
  for (int i = 0; i < 4; ++i) {
    #pragma unroll
    for (int q = 0; q < 4; ++q) {
      int row = rowBase + wr*64 + i*16 + g*4 + q;
      float scale = 1.0f / (float)((row & (L_-1)) + 1);
      size_t rb = (size_t)row * H_;
      #pragma unroll
      for (int n = 0; n < 4; ++n) {
        int c = wc*64 + n*16 + lrow;
        out[rb + c] = x[rb + c] + (acc[i][n][q] + base[n]) * scale;
      }
    }
  }
}

extern "C" void kernel_launch(void* const* d_in, const int* in_sizes, int n_in,
                              void* d_out, int out_size, void* d_ws, size_t ws_size,
                              hipStream_t stream) {
  const float* x  = (const float*)d_in[0];
  const float* Wv = (const float*)d_in[1];
  const float* Wo = (const float*)d_in[2];
  float* out = (float*)d_out;

  char* ws = (char*)d_ws;
  unsigned short* Wbf = (unsigned short*)ws;                    // 128KB
  float* P  = (float*)(ws + 131072);                            // 1MB
  float* Op = (float*)(ws + 131072 + 1048576);                  // 1MB

  hipLaunchKernelGGL(fuse_w_kernel,  dim3(H_),     dim3(H_), 0, stream, Wv, Wo, Wbf);
  hipLaunchKernelGGL(partial_kernel, dim3(CH, B_), dim3(H_), 0, stream, x, P);
  hipLaunchKernelGGL(scan_kernel,    dim3(B_),     dim3(H_), 0, stream, P, Op);
  hipLaunchKernelGGL(main_kernel,    dim3(M_/BM),  dim3(512), 67584, stream,
                     x, Wbf, Op, out);
}

// Round 4
// 81.351 us; speedup vs baseline: 1.1168x; 1.0438x over previous
//
#include <hip/hip_runtime.h>
#include <hip/hip_bf16.h>

// out = x + T @ (x @ Wv^T @ Wo^T), T causal uniform average. fp32 B=16,L=4096,H=256.
// W = Wo@Wv bf16; per 64-row block: Y = bf16(x_tile) @ W^T via MFMA, in-register
// causal prefix (q-add + shfl + i-run), + carry z = Op@W^T, scale, LDS transpose,
// coalesced float4 epilogue with x kept in registers from the stage pass.

#define B_  16
#define L_  4096
#define H_  256
#define M_  (B_*L_)
#define CH  64
#define CHROWS 64
#define BM 64

typedef short short4v __attribute__((ext_vector_type(4)));
typedef short short8  __attribute__((ext_vector_type(8)));
typedef float f32x4   __attribute__((ext_vector_type(4)));

__device__ __forceinline__ unsigned short f2bf(float f) {
  unsigned int u = __builtin_bit_cast(unsigned int, f);
  u += 0x7fffu + ((u >> 16) & 1u);
  return (unsigned short)(u >> 16);
}
__device__ __forceinline__ float bf2f(unsigned short s) {
  return __builtin_bit_cast(float, ((unsigned int)s) << 16);
}

// ---------------- K1: W = Wo @ Wv -> bf16 [H][H] ----------------
__global__ void fuse_w_kernel(const float* __restrict__ Wv,
                              const float* __restrict__ Wo,
                              unsigned short* __restrict__ Wbf) {
  __shared__ float wo[H_];
  int h = blockIdx.x, t = threadIdx.x;
  wo[t] = Wo[h*H_ + t];
  __syncthreads();
  float acc = 0.f;
  #pragma unroll 8
  for (int m = 0; m < H_; ++m) acc += wo[m] * Wv[m*H_ + t];
  Wbf[h*H_ + t] = f2bf(acc);
}

// ---------------- K2: per-64-row-chunk column sums ----------------
__global__ void partial_kernel(const float* __restrict__ x, float* __restrict__ P) {
  int c = blockIdx.x, b = blockIdx.y, t = threadIdx.x;
  const float* p = x + ((size_t)(b*L_ + c*CHROWS))*H_ + t;
  float s = 0.f;
  #pragma unroll 8
  for (int r = 0; r < CHROWS; ++r) s += p[(size_t)r*H_];
  P[(b*CH + c)*H_ + t] = s;
}

// ---------------- K3: exclusive scan of chunk sums ----------------
__global__ void scan_kernel(const float* __restrict__ P, float* __restrict__ O) {
  int b = blockIdx.x, t = threadIdx.x;
  float run = 0.f;
  #pragma unroll
  for (int c = 0; c < CH; ++c) {
    int idx = (b*CH + c)*H_ + t;
    O[idx] = run;
    run += P[idx];
  }
}

// ---------------- K4: main fused kernel ----------------
// 1024 blocks x 512 threads (8 waves). Wave w owns cols [w*32, w*32+32), all 64 rows.
// LDS: [0,32K) X bf16 [64][256] XOR-swizzled  (dead after GEMM)
//      [0,66560) Ytr f32, 64 rows, stride 1040B (reuses X region post-GEMM)
//      [67584,69632) zpart[2][256] f32
__global__ __launch_bounds__(512, 4) void main_kernel(
    const float* __restrict__ x,
    const unsigned short* __restrict__ Wbf,
    const float* __restrict__ Op,          // [M_/64][H] exclusive 64-row prefixes
    float* __restrict__ out) {
  __shared__ __align__(16) char smem[69632];
  float* zpart = (float*)(smem + 67584);

  const int tid = threadIdx.x;
  const int lane = tid & 63, wave = tid >> 6;
  const int rowBase = blockIdx.x * BM;

  // ---- phase A: issue x tile loads (kept for residual) ----
  float4 xk[8];
  const float* xb = x + (size_t)rowBase * H_;
  #pragma unroll
  for (int j = 0; j < 8; ++j)
    xk[j] = *(const float4*)(xb + (j*8 + wave)*H_ + lane*4);

  // ---- Z-dot (hides x-load latency): z[c] = Op_row . W[c], split K over 2 halves ----
  {
    const int c = tid & 255, h = tid >> 8;
    const float* op = Op + (size_t)blockIdx.x * H_ + h*128;
    const unsigned short* wr = Wbf + (size_t)c * H_ + h*128;
    float z = 0.f;
    #pragma unroll 4
    for (int kk = 0; kk < 16; ++kk) {
      short8 w8 = *(const short8*)(wr + kk*8);
      #pragma unroll
      for (int e = 0; e < 8; ++e) z += op[kk*8 + e] * bf2f((unsigned short)w8[e]);
    }
    zpart[h*256 + c] = z;
  }

  // ---- convert + swizzled LDS write of X tile ----
  #pragma unroll
  for (int j = 0; j < 8; ++j) {
    int r = j*8 + wave;
    short4v s;
    s[0] = (short)f2bf(xk[j].x); s[1] = (short)f2bf(xk[j].y);
    s[2] = (short)f2bf(xk[j].z); s[3] = (short)f2bf(xk[j].w);
    *(short4v*)(smem + r*512 + ((lane*8) ^ ((r & 7) << 4))) = s;
  }
  __syncthreads();

  // ---- GEMM: acc = Xbf @ W^T. Wave tile 64 rows x 32 cols ----
  const int wc = wave;
  const int lrow = lane & 15, g = lane >> 4;
  f32x4 acc[4][2] = {};
  #pragma unroll
  for (int k0 = 0; k0 < 4; ++k0) {
    #pragma unroll
    for (int ks = 0; ks < 2; ++ks) {
      short8 bfr[2], af[4];
      #pragma unroll
      for (int n = 0; n < 2; ++n) {
        int wrow = wc*32 + n*16 + lrow;
        bfr[n] = *(const short8*)(Wbf + (size_t)wrow*H_ + k0*64 + ks*32 + g*8);
      }
      #pragma unroll
      for (int i = 0; i < 4; ++i) {
        int ar = i*16 + lrow;
        int cb = (k0*128 + ks*64 + g*16) ^ ((ar & 7) << 4);
        af[i] = *(const short8*)(smem + ar*512 + cb);
      }
      #pragma unroll
      for (int i = 0; i < 4; ++i)
        #pragma unroll
        for (int n = 0; n < 2; ++n)
          acc[i][n] = __builtin_amdgcn_mfma_f32_16x16x32_bf16(af[i], bfr[n], acc[i][n], 0, 0, 0);
    }
  }

  // ---- causal prefix over 64 rows (per wave, per column) + carry + scale ----
  float base[2];
  #pragma unroll
  for (int n = 0; n < 2; ++n) {
    int c = wc*32 + n*16 + lrow;
    base[n] = zpart[c] + zpart[256 + c];
  }
  #pragma unroll
  for (int n = 0; n < 2; ++n) {
    float run = 0.f;
    #pragma unroll
    for (int i = 0; i < 4; ++i) {
      f32x4 a = acc[i][n];
      a[1] += a[0]; a[2] += a[1]; a[3] += a[2];     // q-inclusive
      float Bv = a[3];
      float v = Bv, t;
      t = __shfl_up(v, 16); if (lane >= 16) v += t;
      t = __shfl_up(v, 32); if (lane >= 32) v += t; // g-inclusive of 4-blocks
      float gex = v - Bv;
      float tot = __shfl(v, lrow + 48);             // 16-row total
      float addv = gex + run + base[n];
      #pragma unroll
      for (int q = 0; q < 4; ++q) {
        int row = rowBase + i*16 + g*4 + q;
        float scale = 1.0f / (float)((row & (L_-1)) + 1);
        a[q] = (a[q] + addv) * scale;
      }
      acc[i][n] = a;
      run += tot;
    }
  }
  __syncthreads();                                   // X-LDS dead; reuse for Ytr

  // ---- transpose Y through LDS (stride 1040B) ----
  #pragma unroll
  for (int i = 0; i < 4; ++i)
    #pragma unroll
    for (int n = 0; n < 2; ++n)
      #pragma unroll
      for (int q = 0; q < 4; ++q) {
        int row = i*16 + g*4 + q, col = wc*32 + n*16 + lrow;
        *(float*)(smem + row*1040 + col*4) = acc[i][n][q];
      }
  __syncthreads();

  // ---- coalesced epilogue: out = xk + Ytr ----
  float* ob = out + (size_t)rowBase * H_;
  #pragma unroll
  for (int j = 0; j < 8; ++j) {
    int r = j*8 + wave;
    f32x4 y = *(const f32x4*)(smem + r*1040 + lane*16);
    float4 o;
    o.x = xk[j].x + y[0]; o.y = xk[j].y + y[1];
    o.z = xk[j].z + y[2]; o.w = xk[j].w + y[3];
    *(float4*)(ob + r*H_ + lane*4) = o;
  }
}

extern "C" void kernel_launch(void* const* d_in, const int* in_sizes, int n_in,
                              void* d_out, int out_size, void* d_ws, size_t ws_size,
                              hipStream_t stream) {
  const float* x  = (const float*)d_in[0];
  const float* Wv = (const float*)d_in[1];
  const float* Wo = (const float*)d_in[2];
  float* out = (float*)d_out;

  char* ws = (char*)d_ws;
  unsigned short* Wbf = (unsigned short*)ws;                    // 128KB
  float* P  = (float*)(ws + 131072);                            // 1MB
  float* Op = (float*)(ws + 131072 + 1048576);                  // 1MB

  hipLaunchKernelGGL(fuse_w_kernel,  dim3(H_),     dim3(H_), 0, stream, Wv, Wo, Wbf);
  hipLaunchKernelGGL(partial_kernel, dim3(CH, B_), dim3(H_), 0, stream, x, P);
  hipLaunchKernelGGL(scan_kernel,    dim3(B_),     dim3(H_), 0, stream, P, Op);
  hipLaunchKernelGGL(main_kernel,    dim3(M_/BM),  dim3(512), 0, stream,
                     x, Wbf, Op, out);
}